// Round 3
// baseline (120029.492 us; speedup 1.0000x reference)
//
#include <hip/hip_runtime.h>
#include <hip/hip_cooperative_groups.h>

namespace cg = cooperative_groups;

#define T_   256
#define B_   64
#define H_   1024
#define Hh_  512
#define L_   2
#define K1_  1536
#define MAXF 0.875f

#define NB 64
#define NT 1024
#define CHUNK 256
#define NCHUNK 6

// ---- ws float offsets ----
// Block-tiled weights: Wt[l][blk][k][c]  (c = 16 for zr mats, 8 for g mats)
#define OFF_WZR1 0u          // 2*64*1536*16 = 3,145,728
#define OFF_WG1  3145728u    // 2*64*1536*8  = 1,572,864
#define OFF_WZR2 4718592u    // 3,145,728
#define OFF_WG2  7864320u    // 1,572,864
#define OFF_XT   9437184u    // [1024][64]
#define OFF_HT   9502720u    // [2][1024][64]
#define OFF_ZT   9633792u    // [512][64]
#define OFF_RHT  9666560u    // [512][64]
// total 9,699,328 floats = 38.8 MB

// Retile: src [L][K1][N] -> dst [L][N/C blocks][K1][C]
__global__ __launch_bounds__(256) void retile_w(const float* __restrict__ src,
                                                float* __restrict__ dst,
                                                int N, int C) {
    size_t tid = (size_t)blockIdx.x * 256 + threadIdx.x;
    size_t total = (size_t)L_ * K1_ * N;
    if (tid >= total) return;
    int c = (int)(tid % C);
    int k = (int)((tid / C) % K1_);
    int b = (int)((tid / ((size_t)C * K1_)) % (N / C));
    int l = (int)(tid / ((size_t)C * K1_ * (N / C)));
    dst[tid] = src[((size_t)l * K1_ + k) * N + b * C + c];
}

// Phase GEMM: C[64 rows][C cols] = A[64][1536] @ Wtile + (reduction).
// A layouts are k-major [k][row] (coalesced 256B wave reads, direct global).
// Wtile is this block's [1536][C] slice, streamed through LDS in 6 chunks of
// 256 k via register-prefetch (coalesced float4), consumed as uniform b128.
// K-split across waves; cross-wave reduce via padded LDS partials.
// Returns the reduced dot for tid < 64*C with r = tid/C, c = tid%C.
template<int C>
__device__ __forceinline__ float phase_gemm(const float* __restrict__ Axlo,
                                            const float* __restrict__ Ahi,
                                            const float* __restrict__ Wt,
                                            float* __restrict__ ldsW,
                                            float* __restrict__ part) {
    const int tid  = threadIdx.x;
    const int lane = tid & 63;
    const int w    = tid >> 6;                       // wave 0..15
    constexpr int KW   = (C == 16) ? 8 : 16;         // k-split ways
    constexpr int KPW  = CHUNK / KW;                 // k per wave per chunk
    constexpr int WCH  = CHUNK * C / 4;              // float4s per W chunk
    constexpr int PSTR = C + 1;                      // padded partial stride
    const int kw = (C == 16) ? (w & 7) : w;
    const int c0 = (C == 16) ? ((w >> 3) * 8) : 0;   // col-group base

    float acc[8] = {0.f, 0.f, 0.f, 0.f, 0.f, 0.f, 0.f, 0.f};
    float4 wreg = make_float4(0.f, 0.f, 0.f, 0.f);
    if (tid < WCH) wreg = ((const float4*)Wt)[tid];

    for (int j = 0; j < NCHUNK; ++j) {
        if (tid < WCH) ((float4*)ldsW)[tid] = wreg;
        __syncthreads();
        if (j + 1 < NCHUNK && tid < WCH)
            wreg = ((const float4*)(Wt + (size_t)(j + 1) * CHUNK * C))[tid];
        const float* Ap = (j < 4) ? (Axlo + (size_t)j * CHUNK * 64)
                                  : (Ahi + (size_t)(j - 4) * CHUNK * 64);
        const int klo = kw * KPW;
#pragma unroll 8
        for (int kk = 0; kk < KPW; ++kk) {
            const int kl = klo + kk;
            const float a = Ap[kl * 64 + lane];
            const float4 w0 = *(const float4*)&ldsW[kl * C + c0];
            const float4 w1 = *(const float4*)&ldsW[kl * C + c0 + 4];
            acc[0] = fmaf(a, w0.x, acc[0]); acc[1] = fmaf(a, w0.y, acc[1]);
            acc[2] = fmaf(a, w0.z, acc[2]); acc[3] = fmaf(a, w0.w, acc[3]);
            acc[4] = fmaf(a, w1.x, acc[4]); acc[5] = fmaf(a, w1.y, acc[5]);
            acc[6] = fmaf(a, w1.z, acc[6]); acc[7] = fmaf(a, w1.w, acc[7]);
        }
        __syncthreads();
    }
#pragma unroll
    for (int i = 0; i < 8; ++i)
        part[(kw * 64 + lane) * PSTR + c0 + i] = acc[i];
    __syncthreads();
    float v = 0.f;
    if (tid < 64 * C) {
        const int r = tid / C, c = tid % C;
#pragma unroll
        for (int s = 0; s < KW; ++s) v += part[(s * 64 + r) * PSTR + c];
    }
    return v;
}

__global__ __launch_bounds__(1024, 4) void revgru_main(
    const int* __restrict__ seq, const float* __restrict__ h0,
    const float* __restrict__ emb,
    const float* __restrict__ bzr1, const float* __restrict__ bg1,
    const float* __restrict__ bzr2, const float* __restrict__ bg2,
    float* __restrict__ ws, float* __restrict__ out)
{
    cg::grid_group grid = cg::this_grid();
    const int bi = blockIdx.x, tid = threadIdx.x;
    __shared__ float ldsW[CHUNK * 16];   // 16 KB
    __shared__ float part[16 * 64 * 9];  // 36 KB (covers both shapes, padded)

    float* xT  = ws + OFF_XT;
    float* hT  = ws + OFF_HT;
    float* zT  = ws + OFF_ZT;
    float* rhT = ws + OFF_RHT;
    const float* WZR1 = ws + OFF_WZR1;
    const float* WG1  = ws + OFF_WG1;
    const float* WZR2 = ws + OFF_WZR2;
    const float* WG2  = ws + OFF_WG2;

    const int gtid = bi * NT + tid;
    const int gstride = NB * NT;  // 65536
    for (int i = gtid; i < L_ * B_ * H_; i += gstride) {
        int l = i >> 16, rem = i & 65535, r = rem >> 10, n = rem & 1023;
        hT[((size_t)l * H_ + n) * 64 + r] = h0[i];
    }
    { // xT for t=0 (65536 elems, one per thread)
        int k = gtid >> 6, r = gtid & 63;
        xT[gtid] = emb[(size_t)seq[r] * H_ + k];
    }
    grid.sync();

    for (int t = 0; t < T_; ++t) {
        for (int l = 0; l < L_; ++l) {
            const float* Axlo = (l == 0) ? xT : hT;   // layer-1 x = layer-0 h

            // ---- P1: zr1 = [x, h2] @ Wzr1 ----
            {
                float v = phase_gemm<16>(Axlo, hT + ((size_t)l * H_ + Hh_) * 64,
                                         WZR1 + ((size_t)(l * 64 + bi)) * K1_ * 16,
                                         ldsW, part);
                {
                    int r = tid >> 4, c = tid & 15, n = bi * 16 + c;
                    v += bzr1[l * H_ + n];
                    float s = 1.f / (1.f + __expf(-v));
                    if (n < Hh_) zT[n * 64 + r] = s * MAXF + (1.f - MAXF);
                    else rhT[(n - Hh_) * 64 + r] =
                        s * hT[((size_t)l * H_ + n) * 64 + r];      // r1*h2
                }
                if (l == 1 && t + 1 < T_) {   // prefetch x for t+1
                    int k = gtid >> 6, r = gtid & 63;
                    xT[gtid] = emb[(size_t)seq[(t + 1) * B_ + r] * H_ + k];
                }
                grid.sync();
            }
            // ---- P2: g1 = tanh([x, r1h2]@Wg1 + b); h1 <- z1*h1+(1-z1)*g1 ----
            {
                float v = phase_gemm<8>(Axlo, rhT,
                                        WG1 + ((size_t)(l * 64 + bi)) * K1_ * 8,
                                        ldsW, part);
                if (tid < 512) {
                    int r = tid >> 3, c = tid & 7, n = bi * 8 + c;
                    float g = tanhf(v + bg1[l * Hh_ + n]);
                    float z = zT[n * 64 + r];
                    size_t idx = ((size_t)l * H_ + n) * 64 + r;
                    hT[idx] = z * hT[idx] + (1.f - z) * g;
                }
                grid.sync();
            }
            // ---- P3: zr2 = [x, h1n] @ Wzr2 ----
            {
                float v = phase_gemm<16>(Axlo, hT + (size_t)l * H_ * 64,
                                         WZR2 + ((size_t)(l * 64 + bi)) * K1_ * 16,
                                         ldsW, part);
                {
                    int r = tid >> 4, c = tid & 15, n = bi * 16 + c;
                    v += bzr2[l * H_ + n];
                    float s = 1.f / (1.f + __expf(-v));
                    if (n < Hh_) zT[n * 64 + r] = s * MAXF + (1.f - MAXF);
                    else rhT[(n - Hh_) * 64 + r] =
                        s * hT[((size_t)l * H_ + (n - Hh_)) * 64 + r];  // r2*h1n
                }
                grid.sync();
            }
            // ---- P4: g2 = tanh([x, r2h1n]@Wg2 + b); h2 <- z2*h2+(1-z2)*g2 ----
            {
                float v = phase_gemm<8>(Axlo, rhT,
                                        WG2 + ((size_t)(l * 64 + bi)) * K1_ * 8,
                                        ldsW, part);
                if (tid < 512) {
                    int r = tid >> 3, c = tid & 7, n = bi * 8 + c;
                    float g = tanhf(v + bg2[l * Hh_ + n]);
                    float z = zT[n * 64 + r];
                    size_t idx = ((size_t)l * H_ + Hh_ + n) * 64 + r;
                    hT[idx] = z * hT[idx] + (1.f - z) * g;
                }
                grid.sync();
            }
        }
    }
    for (int i = gtid; i < L_ * B_ * H_; i += gstride) {
        int l = i >> 16, rem = i & 65535, r = rem >> 10, n = rem & 1023;
        out[i] = hT[((size_t)l * H_ + n) * 64 + r];
    }
}

extern "C" void kernel_launch(void* const* d_in, const int* in_sizes, int n_in,
                              void* d_out, int out_size, void* d_ws, size_t ws_size,
                              hipStream_t stream) {
    (void)in_sizes; (void)n_in; (void)out_size; (void)ws_size;
    const int*   seq  = (const int*)  d_in[0];
    const float* h0   = (const float*)d_in[1];
    const float* emb  = (const float*)d_in[2];
    const float* Wzr1 = (const float*)d_in[3];
    const float* bzr1 = (const float*)d_in[4];
    const float* Wg1  = (const float*)d_in[5];
    const float* bg1  = (const float*)d_in[6];
    const float* Wzr2 = (const float*)d_in[7];
    const float* bzr2 = (const float*)d_in[8];
    const float* Wg2  = (const float*)d_in[9];
    const float* bg2  = (const float*)d_in[10];
    float* out = (float*)d_out;
    float* ws  = (float*)d_ws;

    retile_w<<<12288, 256, 0, stream>>>(Wzr1, ws + OFF_WZR1, H_, 16);
    retile_w<<<6144,  256, 0, stream>>>(Wg1,  ws + OFF_WG1,  Hh_, 8);
    retile_w<<<12288, 256, 0, stream>>>(Wzr2, ws + OFF_WZR2, H_, 16);
    retile_w<<<6144,  256, 0, stream>>>(Wg2,  ws + OFF_WG2,  Hh_, 8);

    void* args[] = { &seq, &h0, &emb, &bzr1, &bg1, &bzr2, &bg2, &ws, &out };
    hipLaunchCooperativeKernel((void*)revgru_main, dim3(NB), dim3(NT), args, 0, stream);
}

// Round 4
// 48067.114 us; speedup vs baseline: 2.4971x; 2.4971x over previous
//
#include <hip/hip_runtime.h>

#define T_   256
#define B_   64
#define H_   1024
#define Hh_  512
#define L_   2
#define K1_  1536
#define MAXF 0.875f
#define NBLK 128
#define NT   1024

// ---- ws float offsets ----
#define OFF_WZR1 0u          // [2][64 blk][1536][16]
#define OFF_WG1  3145728u    // [2][64 blk][1536][8]
#define OFF_WZR2 4718592u
#define OFF_WG2  7864320u
#define OFF_XT   9437184u    // [2 buf][1024 k][64 r]
#define OFF_HT   9568256u    // [2 l][2 buf][1024 n][64 r]
#define OFF_ZT   9830400u    // [2 l][512 n][64 r]
#define OFF_RHT  9895936u    // [2 l][512 n][64 r]
#define OFF_CTR  9961472u    // barrier counter (u32)

// Retile: src [L][K1][N] -> dst [L][N/C blocks][K1][C]
__global__ __launch_bounds__(256) void retile_w(const float* __restrict__ src,
                                                float* __restrict__ dst,
                                                int N, int C) {
    size_t tid = (size_t)blockIdx.x * 256 + threadIdx.x;
    size_t total = (size_t)L_ * K1_ * N;
    if (tid >= total) return;
    int c = (int)(tid % C);
    int k = (int)((tid / C) % K1_);
    int b = (int)((tid / ((size_t)C * K1_)) % (N / C));
    int l = (int)(tid / ((size_t)C * K1_ * (N / C)));
    dst[tid] = src[((size_t)l * K1_ + k) * N + b * C + c];
}

// Device-coherent (cross-XCD) activation access: bypasses non-coherent L2 path,
// so NO cache wb/inv fences are ever needed. Weights use normal cached loads.
__device__ __forceinline__ float ld_coh(const float* p) {
    return __hip_atomic_load(p, __ATOMIC_RELAXED, __HIP_MEMORY_SCOPE_AGENT);
}
__device__ __forceinline__ void st_coh(float* p, float v) {
    __hip_atomic_store(p, v, __ATOMIC_RELAXED, __HIP_MEMORY_SCOPE_AGENT);
}

// Fence-free grid barrier: __syncthreads drains vmcnt (stores visible, since all
// shared stores are write-through coherent); monotonic counter, no reset.
__device__ __forceinline__ void gbar(unsigned* ctr, unsigned* target) {
    *target += NBLK;
    __syncthreads();
    if (threadIdx.x == 0) {
        __hip_atomic_fetch_add(ctr, 1u, __ATOMIC_RELAXED, __HIP_MEMORY_SCOPE_AGENT);
        while (__hip_atomic_load(ctr, __ATOMIC_RELAXED, __HIP_MEMORY_SCOPE_AGENT) < *target)
            __builtin_amdgcn_s_sleep(1);
    }
    __syncthreads();
}

// C[64 r][C cols] = A[64][1536] @ Wt[1536][C].  16-way K-split over waves
// (each A element read once, coherent, 8-deep batched). W from L2-hot global,
// wave-uniform address. Cross-wave reduce via LDS atomicAdd (ds_add_f32).
template<int C>
__device__ __forceinline__ float phase_gemm(const float* __restrict__ Axlo,
                                            const float* __restrict__ Ahi,
                                            const float* __restrict__ Wt,
                                            float* __restrict__ red) {
    const int tid  = threadIdx.x;
    const int lane = tid & 63;
    const int w    = __builtin_amdgcn_readfirstlane(tid >> 6);  // 0..15
    const int k0   = w * 96;
    for (int i = tid; i < 64 * (C + 1); i += NT) red[i] = 0.f;
    float acc[C];
#pragma unroll
    for (int c = 0; c < C; ++c) acc[c] = 0.f;
    __syncthreads();
#pragma unroll 1
    for (int kb = 0; kb < 96; kb += 8) {
        float av[8];
#pragma unroll
        for (int j = 0; j < 8; ++j) {
            const int k = k0 + kb + j;
            const float* ap = (k < H_) ? (Axlo + (size_t)k * 64)
                                       : (Ahi + (size_t)(k - H_) * 64);
            av[j] = ld_coh(ap + lane);
        }
#pragma unroll
        for (int j = 0; j < 8; ++j) {
            const float* wr = Wt + (size_t)(k0 + kb + j) * C;
#pragma unroll
            for (int c = 0; c < C; ++c) acc[c] = fmaf(av[j], wr[c], acc[c]);
        }
    }
#pragma unroll
    for (int c = 0; c < C; ++c) atomicAdd(&red[lane * (C + 1) + c], acc[c]);
    __syncthreads();
    float v = 0.f;
    if (tid < 64 * C) v = red[(tid / C) * (C + 1) + (tid % C)];
    return v;
}

__global__ __launch_bounds__(NT) void revgru_main(
    const int* __restrict__ seq, const float* __restrict__ h0,
    const float* __restrict__ emb,
    const float* __restrict__ bzr1, const float* __restrict__ bg1,
    const float* __restrict__ bzr2, const float* __restrict__ bg2,
    float* __restrict__ ws, float* __restrict__ out)
{
    const int bi = blockIdx.x, tid = threadIdx.x;
    const int l = (bi >= 64) ? 1 : 0, bl = bi & 63;
    __shared__ float red[64 * 17];
    unsigned target = 0;

    float* xT  = ws + OFF_XT;
    float* hT  = ws + OFF_HT;
    float* zT  = ws + OFF_ZT;
    float* rhT = ws + OFF_RHT;
    unsigned* ctr = (unsigned*)(ws + OFF_CTR);

    const float* Wz1  = ws + OFF_WZR1 + ((size_t)l * 64 + bl) * K1_ * 16;
    const float* Wg1l = ws + OFF_WG1  + ((size_t)l * 64 + bl) * K1_ * 8;
    const float* Wz2  = ws + OFF_WZR2 + ((size_t)l * 64 + bl) * K1_ * 16;
    const float* Wg2l = ws + OFF_WG2  + ((size_t)l * 64 + bl) * K1_ * 8;

    const int gtid = bi * NT + tid;            // 0..131071, one elem each
    {   // init: hT[l][buf=1] = h0^T (first step reads buf^1 = 1)
        int ll = gtid >> 16, rem = gtid & 65535, r = rem >> 10, n = rem & 1023;
        st_coh(&hT[(((size_t)ll * 2 + 1) * H_ + n) * 64 + r], h0[gtid]);
        if (bi < 64) {  // xT[0] = emb gather for t=0 (65536 elems, blocks 0..63)
            int k = gtid >> 6, rr = gtid & 63;
            st_coh(&xT[gtid], emb[(size_t)seq[rr] * H_ + k]);
        }
    }
    gbar(ctr, &target);

    // Pipelined: L0 blocks process t=s, L1 blocks t=s-1.
    for (int s = 0; s <= T_; ++s) {
        const int t = (l == 0) ? s : s - 1;
        const bool act = (t >= 0) && (t < T_);
        const int buf = t & 1;
        float* hC = hT + ((size_t)l * 2 + buf) * (H_ * 64);        // new state
        float* hP = hT + ((size_t)l * 2 + (buf ^ 1)) * (H_ * 64);  // old state
        const float* Ax = (l == 0) ? (xT + (size_t)buf * (H_ * 64))
                                   : (hT + (size_t)buf * (H_ * 64));  // L0 h(t)
        float* zl  = zT  + (size_t)l * Hh_ * 64;
        float* rhl = rhT + (size_t)l * Hh_ * 64;

        // ---- P1: zr1 = [x, h2_old] @ Wzr1 ----
        if (act) {
            float v = phase_gemm<16>(Ax, hP + Hh_ * 64, Wz1, red);
            int r = tid >> 4, c = tid & 15, n = bl * 16 + c;
            v += bzr1[l * H_ + n];
            float sg = 1.f / (1.f + __expf(-v));
            if (n < Hh_) st_coh(&zl[n * 64 + r], sg * MAXF + (1.f - MAXF));
            else st_coh(&rhl[(n - Hh_) * 64 + r],
                        sg * ld_coh(&hP[(size_t)n * 64 + r]));     // r1*h2_old
            if (l == 0 && t + 1 < T_) {   // prefetch x(t+1)
                int k = gtid >> 6, rr = gtid & 63;
                st_coh(&xT[(size_t)((t + 1) & 1) * (H_ * 64) + k * 64 + rr],
                       emb[(size_t)seq[(t + 1) * B_ + rr] * H_ + k]);
            }
        }
        gbar(ctr, &target);
        // ---- P2: g1; h1_new = z1*h1_old + (1-z1)*g1 ----
        if (act) {
            float v = phase_gemm<8>(Ax, rhl, Wg1l, red);
            if (tid < 512) {
                int r = tid >> 3, c = tid & 7, n = bl * 8 + c;
                float g = tanhf(v + bg1[l * Hh_ + n]);
                float z = ld_coh(&zl[n * 64 + r]);
                float h1o = ld_coh(&hP[(size_t)n * 64 + r]);
                st_coh(&hC[(size_t)n * 64 + r], z * h1o + (1.f - z) * g);
            }
        }
        gbar(ctr, &target);
        // ---- P3: zr2 = [x, h1_new] @ Wzr2 ----
        if (act) {
            float v = phase_gemm<16>(Ax, hC, Wz2, red);
            int r = tid >> 4, c = tid & 15, n = bl * 16 + c;
            v += bzr2[l * H_ + n];
            float sg = 1.f / (1.f + __expf(-v));
            if (n < Hh_) st_coh(&zl[n * 64 + r], sg * MAXF + (1.f - MAXF));
            else st_coh(&rhl[(n - Hh_) * 64 + r],
                        sg * ld_coh(&hC[(size_t)(n - Hh_) * 64 + r])); // r2*h1n
        }
        gbar(ctr, &target);
        // ---- P4: g2; h2_new = z2*h2_old + (1-z2)*g2 ----
        if (act) {
            float v = phase_gemm<8>(Ax, rhl, Wg2l, red);
            if (tid < 512) {
                int r = tid >> 3, c = tid & 7, n = bl * 8 + c;
                float g = tanhf(v + bg2[l * Hh_ + n]);
                float z = ld_coh(&zl[n * 64 + r]);
                float h2o = ld_coh(&hP[(size_t)(Hh_ + n) * 64 + r]);
                st_coh(&hC[(size_t)(Hh_ + n) * 64 + r], z * h2o + (1.f - z) * g);
            }
        }
        gbar(ctr, &target);
    }
    {   // out[l][r][n] = hT[l][1][n][r]  (final t=255 -> buf 1 for both layers)
        int ll = gtid >> 16, rem = gtid & 65535, r = rem >> 10, n = rem & 1023;
        out[gtid] = ld_coh(&hT[(((size_t)ll * 2 + 1) * H_ + n) * 64 + r]);
    }
}

extern "C" void kernel_launch(void* const* d_in, const int* in_sizes, int n_in,
                              void* d_out, int out_size, void* d_ws, size_t ws_size,
                              hipStream_t stream) {
    (void)in_sizes; (void)n_in; (void)out_size; (void)ws_size;
    const int*   seq  = (const int*)  d_in[0];
    const float* h0   = (const float*)d_in[1];
    const float* emb  = (const float*)d_in[2];
    const float* Wzr1 = (const float*)d_in[3];
    const float* bzr1 = (const float*)d_in[4];
    const float* Wg1  = (const float*)d_in[5];
    const float* bg1  = (const float*)d_in[6];
    const float* Wzr2 = (const float*)d_in[7];
    const float* bzr2 = (const float*)d_in[8];
    const float* Wg2  = (const float*)d_in[9];
    const float* bg2  = (const float*)d_in[10];
    float* out = (float*)d_out;
    float* ws  = (float*)d_ws;

    hipMemsetAsync((char*)d_ws + (size_t)OFF_CTR * 4, 0, 64, stream);
    retile_w<<<12288, 256, 0, stream>>>(Wzr1, ws + OFF_WZR1, H_, 16);
    retile_w<<<6144,  256, 0, stream>>>(Wg1,  ws + OFF_WG1,  Hh_, 8);
    retile_w<<<12288, 256, 0, stream>>>(Wzr2, ws + OFF_WZR2, H_, 16);
    retile_w<<<6144,  256, 0, stream>>>(Wg2,  ws + OFF_WG2,  Hh_, 8);

    void* args[] = { &seq, &h0, &emb, &bzr1, &bg1, &bzr2, &bg2, &ws, &out };
    hipLaunchCooperativeKernel((void*)revgru_main, dim3(NBLK), dim3(NT),
                               args, 0, stream);
}